// Round 1
// baseline (2303.970 us; speedup 1.0000x reference)
//
#include <hip/hip_runtime.h>

#define NN 50000
#define NE 300000
#define EMB 256
#define HID 512
#define NL 5

// ---------------- node encoder: h = type_emb[id] + depth_emb[clip(depth)] ----------------
__global__ __launch_bounds__(256) void k_init_h(const int* __restrict__ ids,
    const int* __restrict__ depth, const float* __restrict__ temb,
    const float* __restrict__ demb, float* __restrict__ h) {
  int gid = blockIdx.x * 256 + threadIdx.x;
  int row = gid >> 6;
  if (row >= NN) return;
  int c4 = (gid & 63) << 2;
  int id = ids[row];
  int d = depth[row]; d = d < 0 ? 0 : (d > 20 ? 20 : d);
  float4 a = *(const float4*)&temb[id * EMB + c4];
  float4 b = *(const float4*)&demb[d * EMB + c4];
  *(float4*)&h[row * EMB + c4] = make_float4(a.x + b.x, a.y + b.y, a.z + b.z, a.w + b.w);
}

// ---------------- CSR build (counting sort by dst) ----------------
__global__ __launch_bounds__(256) void k_count(const int* __restrict__ dst, int* __restrict__ deg) {
  int e = blockIdx.x * 256 + threadIdx.x;
  if (e < NE) atomicAdd(&deg[dst[e]], 1);
}

// exclusive scan over deg[NN] -> row_off, 1024 elems per block
__global__ __launch_bounds__(256) void k_scan1(const int* __restrict__ deg,
    int* __restrict__ row_off, int* __restrict__ bsums) {
  __shared__ int lds[256];
  int b = blockIdx.x, t = threadIdx.x;
  int base = b * 1024;
  int v[4]; int s = 0;
  for (int i = 0; i < 4; ++i) {
    int idx = base + t * 4 + i;
    v[i] = (idx < NN) ? deg[idx] : 0;
    s += v[i];
  }
  lds[t] = s; __syncthreads();
  for (int off = 1; off < 256; off <<= 1) {
    int x = (t >= off) ? lds[t - off] : 0; __syncthreads();
    lds[t] += x; __syncthreads();
  }
  int run = (t > 0) ? lds[t - 1] : 0;
  if (t == 255) bsums[b] = lds[255];
  for (int i = 0; i < 4; ++i) {
    int idx = base + t * 4 + i;
    if (idx < NN) row_off[idx] = run;
    run += v[i];
  }
}
__global__ __launch_bounds__(256) void k_scan2(int* __restrict__ bsums, int nb) {
  __shared__ int lds[256];
  int t = threadIdx.x;
  int v = (t < nb) ? bsums[t] : 0;
  lds[t] = v; __syncthreads();
  for (int off = 1; off < 256; off <<= 1) {
    int x = (t >= off) ? lds[t - off] : 0; __syncthreads();
    lds[t] += x; __syncthreads();
  }
  if (t < nb) bsums[t] = (t > 0) ? lds[t - 1] : 0;
}
__global__ __launch_bounds__(256) void k_scan3(int* __restrict__ row_off, const int* __restrict__ bsums) {
  int b = blockIdx.x, t = threadIdx.x;
  int base = b * 1024;
  int add = bsums[b];
  for (int i = 0; i < 4; ++i) {
    int idx = base + t * 4 + i;
    if (idx < NN) row_off[idx] += add;
  }
  if (b == 0 && t == 0) row_off[NN] = NE;
}
__global__ __launch_bounds__(256) void k_copy(const int* __restrict__ a, int* __restrict__ b) {
  int i = blockIdx.x * 256 + threadIdx.x;
  if (i < NN) b[i] = a[i];
}
__global__ __launch_bounds__(256) void k_fill(const int* __restrict__ src, const int* __restrict__ dst,
    const float* __restrict__ attr, int* __restrict__ cursor,
    int* __restrict__ ssrc, float2* __restrict__ sattr) {
  int e = blockIdx.x * 256 + threadIdx.x;
  if (e >= NE) return;
  int d = dst[e];
  int p = atomicAdd(&cursor[d], 1);
  ssrc[p] = src[e];
  sattr[p] = make_float2(attr[2 * e], attr[2 * e + 1]);
}

// ---------------- per-layer: agg + z = (1+eps)*h + sum relu(h[src]+e) ----------------
// one wave per node; lane c handles channels 4c..4c+3
__global__ __launch_bounds__(256) void k_aggregate(const float* __restrict__ h,
    const int* __restrict__ row_off, const int* __restrict__ ssrc,
    const float2* __restrict__ sattr, const float* __restrict__ We_l,
    const float* __restrict__ be_l, const float* __restrict__ epsp, int layer,
    float* __restrict__ z) {
  int wid = (blockIdx.x * 256 + threadIdx.x) >> 6;
  if (wid >= NN) return;
  int c4 = (threadIdx.x & 63) << 2;
  float4 w0 = *(const float4*)&We_l[c4];
  float4 w1 = *(const float4*)&We_l[EMB + c4];
  float4 bb = *(const float4*)&be_l[c4];
  float4 acc = make_float4(0.f, 0.f, 0.f, 0.f);
  int k0 = row_off[wid], k1 = row_off[wid + 1];
  for (int k = k0; k < k1; ++k) {
    int s = ssrc[k];
    float2 a = sattr[k];
    float4 hv = *(const float4*)&h[s * EMB + c4];
    acc.x += fmaxf(hv.x + a.x * w0.x + a.y * w1.x + bb.x, 0.f);
    acc.y += fmaxf(hv.y + a.x * w0.y + a.y * w1.y + bb.y, 0.f);
    acc.z += fmaxf(hv.z + a.x * w0.z + a.y * w1.z + bb.z, 0.f);
    acc.w += fmaxf(hv.w + a.x * w0.w + a.y * w1.w + bb.w, 0.f);
  }
  float e1 = 1.0f + epsp[layer];
  float4 hv = *(const float4*)&h[wid * EMB + c4];
  *(float4*)&z[wid * EMB + c4] = make_float4(
      e1 * hv.x + acc.x, e1 * hv.y + acc.y, e1 * hv.z + acc.z, e1 * hv.w + acc.w);
}

// ---------------- GEMM1: y = z @ W1 + b1, plus column sum/sumsq for BN ----------------
// BM=128, BN=128, BK=16, 256 threads (16x16), 8x8 per thread
__global__ __launch_bounds__(256) void k_gemm1(const float* __restrict__ Z,
    const float* __restrict__ W, const float* __restrict__ bias,
    float* __restrict__ Y, float* __restrict__ colsum, float* __restrict__ colsq) {
  __shared__ float zs[16][132];   // [k][row], padded
  __shared__ float wsm[16][128];  // [k][col]
  int row0 = blockIdx.x * 128, col0 = blockIdx.y * 128;
  int tid = threadIdx.x;
  int tx = tid & 15, ty = tid >> 4;
  float acc[8][8] = {};
  for (int k0 = 0; k0 < EMB; k0 += 16) {
    for (int it = 0; it < 2; ++it) {
      int li = tid + it * 256;          // 0..511
      int r = li >> 2, q = li & 3;
      float4 v = make_float4(0.f, 0.f, 0.f, 0.f);
      int gr = row0 + r;
      if (gr < NN) v = *(const float4*)&Z[gr * EMB + k0 + q * 4];
      zs[q * 4 + 0][r] = v.x; zs[q * 4 + 1][r] = v.y;
      zs[q * 4 + 2][r] = v.z; zs[q * 4 + 3][r] = v.w;
    }
    for (int it = 0; it < 2; ++it) {
      int li = tid + it * 256;          // 0..511
      int kk = li >> 5, cq = li & 31;
      float4 v = *(const float4*)&W[(k0 + kk) * HID + col0 + cq * 4];
      *(float4*)&wsm[kk][cq * 4] = v;
    }
    __syncthreads();
    for (int kk = 0; kk < 16; ++kk) {
      float a[8], b[8];
      *(float4*)&a[0] = *(const float4*)&zs[kk][ty * 8];
      *(float4*)&a[4] = *(const float4*)&zs[kk][ty * 8 + 4];
      *(float4*)&b[0] = *(const float4*)&wsm[kk][tx * 8];
      *(float4*)&b[4] = *(const float4*)&wsm[kk][tx * 8 + 4];
#pragma unroll
      for (int i = 0; i < 8; ++i)
#pragma unroll
        for (int j = 0; j < 8; ++j) acc[i][j] += a[i] * b[j];
    }
    __syncthreads();
  }
  float cs[8] = {}, cq2[8] = {};
  float bj[8];
#pragma unroll
  for (int j = 0; j < 8; ++j) bj[j] = bias[col0 + tx * 8 + j];
#pragma unroll
  for (int i = 0; i < 8; ++i) {
    int gr = row0 + ty * 8 + i;
    if (gr < NN) {
      float4 o1, o2;
      float v0 = acc[i][0] + bj[0], v1 = acc[i][1] + bj[1], v2 = acc[i][2] + bj[2], v3 = acc[i][3] + bj[3];
      float v4 = acc[i][4] + bj[4], v5 = acc[i][5] + bj[5], v6 = acc[i][6] + bj[6], v7 = acc[i][7] + bj[7];
      o1 = make_float4(v0, v1, v2, v3); o2 = make_float4(v4, v5, v6, v7);
      *(float4*)&Y[gr * HID + col0 + tx * 8] = o1;
      *(float4*)&Y[gr * HID + col0 + tx * 8 + 4] = o2;
      cs[0] += v0; cs[1] += v1; cs[2] += v2; cs[3] += v3;
      cs[4] += v4; cs[5] += v5; cs[6] += v6; cs[7] += v7;
      cq2[0] += v0 * v0; cq2[1] += v1 * v1; cq2[2] += v2 * v2; cq2[3] += v3 * v3;
      cq2[4] += v4 * v4; cq2[5] += v5 * v5; cq2[6] += v6 * v6; cq2[7] += v7 * v7;
    }
  }
  // block-level column reduction in LDS (reuse zs: 2112 floats >= 2048)
  float* red = &zs[0][0];
  __syncthreads();
#pragma unroll
  for (int j = 0; j < 8; ++j) red[ty * 128 + tx * 8 + j] = cs[j];
  __syncthreads();
  if (tid < 128) {
    float s = 0.f;
    for (int t = 0; t < 16; ++t) s += red[t * 128 + tid];
    atomicAdd(&colsum[col0 + tid], s);
  }
  __syncthreads();
#pragma unroll
  for (int j = 0; j < 8; ++j) red[ty * 128 + tx * 8 + j] = cq2[j];
  __syncthreads();
  if (tid < 128) {
    float s = 0.f;
    for (int t = 0; t < 16; ++t) s += red[t * 128 + tid];
    atomicAdd(&colsq[col0 + tid], s);
  }
}

// ---------------- BN finalize: scale/shift per column ----------------
__global__ void k_bnfin(const float* __restrict__ colsum, const float* __restrict__ colsq,
    const float* __restrict__ gamma, const float* __restrict__ beta,
    float* __restrict__ scale, float* __restrict__ shift) {
  int c = threadIdx.x;
  float inv_n = 1.0f / (float)NN;
  float mu = colsum[c] * inv_n;
  float var = colsq[c] * inv_n - mu * mu;
  float rstd = rsqrtf(var + 1e-5f);
  float sc = rstd * gamma[c];
  scale[c] = sc;
  shift[c] = beta[c] - mu * sc;
}

// ---------------- GEMM2: h = [relu?]( relu(y*scale+shift) @ W2 + b2 ) ----------------
__global__ __launch_bounds__(256) void k_gemm2(const float* __restrict__ Y,
    const float* __restrict__ W, const float* __restrict__ bias,
    const float* __restrict__ scale, const float* __restrict__ shift,
    float* __restrict__ H, int relu_out) {
  __shared__ float ys[16][132];
  __shared__ float wsm[16][128];
  int row0 = blockIdx.x * 128, col0 = blockIdx.y * 128;
  int tid = threadIdx.x;
  int tx = tid & 15, ty = tid >> 4;
  float acc[8][8] = {};
  for (int k0 = 0; k0 < HID; k0 += 16) {
    for (int it = 0; it < 2; ++it) {
      int li = tid + it * 256;
      int r = li >> 2, q = li & 3;
      float4 v = make_float4(0.f, 0.f, 0.f, 0.f);
      int gr = row0 + r;
      if (gr < NN) v = *(const float4*)&Y[gr * HID + k0 + q * 4];
      float4 s4 = *(const float4*)&scale[k0 + q * 4];
      float4 t4 = *(const float4*)&shift[k0 + q * 4];
      v.x = fmaxf(v.x * s4.x + t4.x, 0.f);
      v.y = fmaxf(v.y * s4.y + t4.y, 0.f);
      v.z = fmaxf(v.z * s4.z + t4.z, 0.f);
      v.w = fmaxf(v.w * s4.w + t4.w, 0.f);
      ys[q * 4 + 0][r] = v.x; ys[q * 4 + 1][r] = v.y;
      ys[q * 4 + 2][r] = v.z; ys[q * 4 + 3][r] = v.w;
    }
    for (int it = 0; it < 2; ++it) {
      int li = tid + it * 256;
      int kk = li >> 5, cq = li & 31;
      float4 v = *(const float4*)&W[(k0 + kk) * EMB + col0 + cq * 4];
      *(float4*)&wsm[kk][cq * 4] = v;
    }
    __syncthreads();
    for (int kk = 0; kk < 16; ++kk) {
      float a[8], b[8];
      *(float4*)&a[0] = *(const float4*)&ys[kk][ty * 8];
      *(float4*)&a[4] = *(const float4*)&ys[kk][ty * 8 + 4];
      *(float4*)&b[0] = *(const float4*)&wsm[kk][tx * 8];
      *(float4*)&b[4] = *(const float4*)&wsm[kk][tx * 8 + 4];
#pragma unroll
      for (int i = 0; i < 8; ++i)
#pragma unroll
        for (int j = 0; j < 8; ++j) acc[i][j] += a[i] * b[j];
    }
    __syncthreads();
  }
  float bj[8];
#pragma unroll
  for (int j = 0; j < 8; ++j) bj[j] = bias[col0 + tx * 8 + j];
#pragma unroll
  for (int i = 0; i < 8; ++i) {
    int gr = row0 + ty * 8 + i;
    if (gr < NN) {
      float v[8];
#pragma unroll
      for (int j = 0; j < 8; ++j) {
        v[j] = acc[i][j] + bj[j];
        if (relu_out) v[j] = fmaxf(v[j], 0.f);
      }
      *(float4*)&H[gr * EMB + col0 + tx * 8] = make_float4(v[0], v[1], v[2], v[3]);
      *(float4*)&H[gr * EMB + col0 + tx * 8 + 4] = make_float4(v[4], v[5], v[6], v[7]);
    }
  }
}

extern "C" void kernel_launch(void* const* d_in, const int* in_sizes, int n_in,
                              void* d_out, int out_size, void* d_ws, size_t ws_size,
                              hipStream_t stream) {
  (void)in_sizes; (void)n_in; (void)out_size; (void)ws_size;
  const int* node_ids    = (const int*)d_in[0];
  const int* node_depth  = (const int*)d_in[1];
  const int* edge_index  = (const int*)d_in[2];
  const float* edge_attr = (const float*)d_in[3];
  const float* temb      = (const float*)d_in[4];
  const float* demb      = (const float*)d_in[5];
  const float* We        = (const float*)d_in[6];
  const float* be        = (const float*)d_in[7];
  const float* W1        = (const float*)d_in[8];
  const float* b1        = (const float*)d_in[9];
  const float* gamma_    = (const float*)d_in[10];
  const float* beta_     = (const float*)d_in[11];
  const float* W2        = (const float*)d_in[12];
  const float* b2        = (const float*)d_in[13];
  const float* epsp      = (const float*)d_in[14];
  float* h = (float*)d_out;

  char* ws = (char*)d_ws;
  size_t off = 0;
  auto alloc = [&](size_t bytes) -> void* {
    void* p = ws + off;
    off = (off + bytes + 255) & ~(size_t)255;
    return p;
  };
  float* z      = (float*)alloc(sizeof(float) * (size_t)NN * EMB);   // 51.2 MB
  float* y      = (float*)alloc(sizeof(float) * (size_t)NN * HID);   // 102.4 MB
  int* deg      = (int*)alloc(sizeof(int) * NN);
  int* row_off  = (int*)alloc(sizeof(int) * (NN + 1));
  int* cursor   = (int*)alloc(sizeof(int) * NN);
  int* ssrc     = (int*)alloc(sizeof(int) * NE);
  float2* sattr = (float2*)alloc(sizeof(float2) * NE);
  int* bsums    = (int*)alloc(sizeof(int) * 256);
  float* colsum = (float*)alloc(sizeof(float) * HID * 2);
  float* colsq  = colsum + HID;
  float* scale  = (float*)alloc(sizeof(float) * HID);
  float* shift  = (float*)alloc(sizeof(float) * HID);

  const int* e_src = edge_index;
  const int* e_dst = edge_index + NE;

  k_init_h<<<(NN * 64) / 256, 256, 0, stream>>>(node_ids, node_depth, temb, demb, h);
  hipMemsetAsync(deg, 0, sizeof(int) * NN, stream);
  k_count<<<(NE + 255) / 256, 256, 0, stream>>>(e_dst, deg);
  k_scan1<<<49, 256, 0, stream>>>(deg, row_off, bsums);
  k_scan2<<<1, 256, 0, stream>>>(bsums, 49);
  k_scan3<<<49, 256, 0, stream>>>(row_off, bsums);
  k_copy<<<(NN + 255) / 256, 256, 0, stream>>>(row_off, cursor);
  k_fill<<<(NE + 255) / 256, 256, 0, stream>>>(e_src, e_dst, edge_attr, cursor, ssrc, sattr);

  for (int l = 0; l < NL; ++l) {
    k_aggregate<<<(NN * 64) / 256, 256, 0, stream>>>(
        h, row_off, ssrc, sattr, We + (size_t)l * 2 * EMB, be + (size_t)l * EMB, epsp, l, z);
    hipMemsetAsync(colsum, 0, sizeof(float) * HID * 2, stream);
    dim3 g1((NN + 127) / 128, HID / 128);
    k_gemm1<<<g1, 256, 0, stream>>>(z, W1 + (size_t)l * EMB * HID, b1 + (size_t)l * HID,
                                    y, colsum, colsq);
    k_bnfin<<<1, HID, 0, stream>>>(colsum, colsq, gamma_ + (size_t)l * HID,
                                   beta_ + (size_t)l * HID, scale, shift);
    dim3 g2((NN + 127) / 128, EMB / 128);
    k_gemm2<<<g2, 256, 0, stream>>>(y, W2 + (size_t)l * HID * EMB, b2 + (size_t)l * EMB,
                                    scale, shift, h, (l < NL - 1) ? 1 : 0);
  }
}

// Round 4
// 1131.876 us; speedup vs baseline: 2.0355x; 2.0355x over previous
//
#include <hip/hip_runtime.h>

#define NN 50000
#define NE 300000
#define EMB 256
#define HID 512
#define NL 5

typedef __attribute__((ext_vector_type(8))) short bf16x8;
typedef __attribute__((ext_vector_type(4))) float f32x4;
typedef __attribute__((ext_vector_type(8))) unsigned short u16x8;
typedef __attribute__((ext_vector_type(4))) unsigned short u16x4;

union U8u { u16x8 v; unsigned short s[8]; };

__device__ __forceinline__ float bf2f(unsigned short u) {
  union { unsigned int i; float f; } c; c.i = ((unsigned int)u) << 16; return c.f;
}
__device__ __forceinline__ unsigned short f2bf(float f) {
  union { float f; unsigned int i; } c; c.f = f;
  unsigned int r = c.i + 0x7FFF + ((c.i >> 16) & 1);
  return (unsigned short)(r >> 16);
}

// ---------------- node encoder ----------------
__global__ __launch_bounds__(256) void k_init_h(const int* __restrict__ ids,
    const int* __restrict__ depth, const float* __restrict__ temb,
    const float* __restrict__ demb, float* __restrict__ h) {
  int gid = blockIdx.x * 256 + threadIdx.x;
  int row = gid >> 6;
  if (row >= NN) return;
  int c4 = (gid & 63) << 2;
  int id = ids[row];
  int d = depth[row]; d = d < 0 ? 0 : (d > 20 ? 20 : d);
  float4 a = *(const float4*)&temb[id * EMB + c4];
  float4 b = *(const float4*)&demb[d * EMB + c4];
  *(float4*)&h[row * EMB + c4] = make_float4(a.x + b.x, a.y + b.y, a.z + b.z, a.w + b.w);
}

// ---------------- CSR build ----------------
__global__ __launch_bounds__(256) void k_count(const int* __restrict__ dst, int* __restrict__ deg) {
  int e = blockIdx.x * 256 + threadIdx.x;
  if (e < NE) atomicAdd(&deg[dst[e]], 1);
}
__global__ __launch_bounds__(256) void k_scan1(const int* __restrict__ deg,
    int* __restrict__ row_off, int* __restrict__ bsums) {
  __shared__ int lds[256];
  int b = blockIdx.x, t = threadIdx.x;
  int base = b * 1024;
  int v[4]; int s = 0;
  for (int i = 0; i < 4; ++i) {
    int idx = base + t * 4 + i;
    v[i] = (idx < NN) ? deg[idx] : 0;
    s += v[i];
  }
  lds[t] = s; __syncthreads();
  for (int off = 1; off < 256; off <<= 1) {
    int x = (t >= off) ? lds[t - off] : 0; __syncthreads();
    lds[t] += x; __syncthreads();
  }
  int run = (t > 0) ? lds[t - 1] : 0;
  if (t == 255) bsums[b] = lds[255];
  for (int i = 0; i < 4; ++i) {
    int idx = base + t * 4 + i;
    if (idx < NN) row_off[idx] = run;
    run += v[i];
  }
}
__global__ __launch_bounds__(256) void k_scan2(int* __restrict__ bsums, int nb) {
  __shared__ int lds[256];
  int t = threadIdx.x;
  int v = (t < nb) ? bsums[t] : 0;
  lds[t] = v; __syncthreads();
  for (int off = 1; off < 256; off <<= 1) {
    int x = (t >= off) ? lds[t - off] : 0; __syncthreads();
    lds[t] += x; __syncthreads();
  }
  if (t < nb) bsums[t] = (t > 0) ? lds[t - 1] : 0;
}
__global__ __launch_bounds__(256) void k_scan3(int* __restrict__ row_off, const int* __restrict__ bsums) {
  int b = blockIdx.x, t = threadIdx.x;
  int base = b * 1024;
  int add = bsums[b];
  for (int i = 0; i < 4; ++i) {
    int idx = base + t * 4 + i;
    if (idx < NN) row_off[idx] += add;
  }
  if (b == 0 && t == 0) row_off[NN] = NE;
}
__global__ __launch_bounds__(256) void k_copy(const int* __restrict__ a, int* __restrict__ b) {
  int i = blockIdx.x * 256 + threadIdx.x;
  if (i < NN) b[i] = a[i];
}
__global__ __launch_bounds__(256) void k_fill(const int* __restrict__ src, const int* __restrict__ dst,
    const float* __restrict__ attr, int* __restrict__ cursor,
    int* __restrict__ ssrc, float2* __restrict__ sattr) {
  int e = blockIdx.x * 256 + threadIdx.x;
  if (e >= NE) return;
  int d = dst[e];
  int p = atomicAdd(&cursor[d], 1);
  ssrc[p] = src[e];
  sattr[p] = make_float2(attr[2 * e], attr[2 * e + 1]);
}

// ---------------- weight transpose + bf16 convert: W[R][C] -> Wt[C][R] ----------------
__global__ __launch_bounds__(256) void k_convW(const float* __restrict__ W,
    unsigned short* __restrict__ Wt, int R, int C) {
  __shared__ float t[32][33];
  int l = blockIdx.z;
  const float* Wl = W + (size_t)l * R * C;
  unsigned short* Wtl = Wt + (size_t)l * R * C;
  int c0 = blockIdx.x * 32, r0 = blockIdx.y * 32;
  int tx = threadIdx.x & 31, ty = threadIdx.x >> 5;  // ty 0..7
  for (int i = 0; i < 32; i += 8)
    t[ty + i][tx] = Wl[(size_t)(r0 + ty + i) * C + c0 + tx];
  __syncthreads();
  for (int i = 0; i < 32; i += 8)
    Wtl[(size_t)(c0 + ty + i) * R + r0 + tx] = f2bf(t[tx][ty + i]);
}

// ---------------- per-layer aggregate: z = (1+eps)*h + sum relu(h[src]+e), bf16 out ----------------
__global__ __launch_bounds__(256) void k_aggregate(const float* __restrict__ h,
    const int* __restrict__ row_off, const int* __restrict__ ssrc,
    const float2* __restrict__ sattr, const float* __restrict__ We_l,
    const float* __restrict__ be_l, const float* __restrict__ epsp, int layer,
    unsigned short* __restrict__ z) {
  int wid = (blockIdx.x * 256 + threadIdx.x) >> 6;
  if (wid >= NN) return;
  int c4 = (threadIdx.x & 63) << 2;
  float4 w0 = *(const float4*)&We_l[c4];
  float4 w1 = *(const float4*)&We_l[EMB + c4];
  float4 bb = *(const float4*)&be_l[c4];
  float4 acc = make_float4(0.f, 0.f, 0.f, 0.f);
  int k0 = row_off[wid], k1 = row_off[wid + 1];
  for (int k = k0; k < k1; ++k) {
    int s = ssrc[k];
    float2 a = sattr[k];
    float4 hv = *(const float4*)&h[(size_t)s * EMB + c4];
    acc.x += fmaxf(hv.x + a.x * w0.x + a.y * w1.x + bb.x, 0.f);
    acc.y += fmaxf(hv.y + a.x * w0.y + a.y * w1.y + bb.y, 0.f);
    acc.z += fmaxf(hv.z + a.x * w0.z + a.y * w1.z + bb.z, 0.f);
    acc.w += fmaxf(hv.w + a.x * w0.w + a.y * w1.w + bb.w, 0.f);
  }
  float e1 = 1.0f + epsp[layer];
  float4 hv = *(const float4*)&h[(size_t)wid * EMB + c4];
  u16x4 o;
  o[0] = f2bf(e1 * hv.x + acc.x);
  o[1] = f2bf(e1 * hv.y + acc.y);
  o[2] = f2bf(e1 * hv.z + acc.z);
  o[3] = f2bf(e1 * hv.w + acc.w);
  *(u16x4*)&z[(size_t)wid * EMB + c4] = o;
}

// ---------------- MFMA GEMM: C[M x NC] = A[M x K](bf16) @ Bt[NC x K](bf16)^T ----------------
// MODE 0: +bias -> write bf16 Y, accumulate col sum/sumsq (fp32 atomics)
// MODE 1: A-staging applies relu(a*scale[k]+shift[k]); +bias, relu, write f32 H
// MODE 2: same as 1 but no output relu
template<int K, int NC, int MODE>
__global__ __launch_bounds__(256) void k_mfma_gemm(
    const unsigned short* __restrict__ A, const unsigned short* __restrict__ Bt,
    const float* __restrict__ bias, const float* __restrict__ scale,
    const float* __restrict__ shift, unsigned short* __restrict__ Ybf,
    float* __restrict__ Hout, float* __restrict__ colsum, float* __restrict__ colsq) {
  __shared__ __align__(16) unsigned short lA[2][128 * 32];
  __shared__ __align__(16) unsigned short lB[2][128 * 32];
  int row0 = blockIdx.x * 128, col0 = blockIdx.y * 128;
  int tid = threadIdx.x, lane = tid & 63, wave = tid >> 6;
  int wr = (wave >> 1) * 64, wc = (wave & 1) * 64;
  int lr = lane & 15, lg = lane >> 4;
  f32x4 acc[4][4] = {};

  auto stageA = [&](int buf, int k0) {
#pragma unroll
    for (int r = 0; r < 2; ++r) {
      int off8 = (r * 256 + tid) * 8;      // bf16-elem offset in 128x32 tile
      int row = off8 >> 5;
      int kk = off8 & 31;
      int gr = row0 + row; if (gr > NN - 1) gr = NN - 1;
      u16x8 v = *(const u16x8*)&A[(size_t)gr * K + k0 + kk];
      if constexpr (MODE >= 1) {
        f32x4 sc0 = *(const f32x4*)&scale[k0 + kk];
        f32x4 sc1 = *(const f32x4*)&scale[k0 + kk + 4];
        f32x4 sh0 = *(const f32x4*)&shift[k0 + kk];
        f32x4 sh1 = *(const f32x4*)&shift[k0 + kk + 4];
        U8u u; u.v = v;
#pragma unroll
        for (int j = 0; j < 4; ++j)
          u.s[j] = f2bf(fmaxf(bf2f(u.s[j]) * sc0[j] + sh0[j], 0.f));
#pragma unroll
        for (int j = 0; j < 4; ++j)
          u.s[4 + j] = f2bf(fmaxf(bf2f(u.s[4 + j]) * sc1[j] + sh1[j], 0.f));
        v = u.v;
      }
      *(u16x8*)&lA[buf][off8] = v;
    }
  };
  auto stageB = [&](int buf, int k0) {
#pragma unroll
    for (int r = 0; r < 2; ++r) {
      int off8 = (r * 256 + tid) * 8;
      int col = off8 >> 5;
      int kk = off8 & 31;
      *(u16x8*)&lB[buf][off8] = *(const u16x8*)&Bt[(size_t)(col0 + col) * K + k0 + kk];
    }
  };

  int cur = 0;
  stageA(0, 0); stageB(0, 0);
  __syncthreads();
  for (int kt = 0; kt < K / 32; ++kt) {
    if (kt + 1 < K / 32) { stageA(cur ^ 1, (kt + 1) * 32); stageB(cur ^ 1, (kt + 1) * 32); }
    bf16x8 af[4], bfr[4];
#pragma unroll
    for (int m = 0; m < 4; ++m)
      af[m] = *(const bf16x8*)&lA[cur][(wr + m * 16 + lr) * 32 + lg * 8];
#pragma unroll
    for (int n = 0; n < 4; ++n)
      bfr[n] = *(const bf16x8*)&lB[cur][(wc + n * 16 + lr) * 32 + lg * 8];
#pragma unroll
    for (int m = 0; m < 4; ++m)
#pragma unroll
      for (int n = 0; n < 4; ++n)
        acc[m][n] = __builtin_amdgcn_mfma_f32_16x16x32_bf16(af[m], bfr[n], acc[m][n], 0, 0, 0);
    __syncthreads();
    cur ^= 1;
  }

  if constexpr (MODE == 0) {
    float cs[4] = {}, cq[4] = {};
#pragma unroll
    for (int n = 0; n < 4; ++n) {
      int gc = col0 + wc + n * 16 + lr;
      float bv = bias[gc];
#pragma unroll
      for (int m = 0; m < 4; ++m) {
        int grb = row0 + wr + m * 16 + lg * 4;
#pragma unroll
        for (int j = 0; j < 4; ++j) {
          int gr = grb + j;
          if (gr < NN) {
            float v = acc[m][n][j] + bv;
            Ybf[(size_t)gr * NC + gc] = f2bf(v);
            cs[n] += v; cq[n] += v * v;
          }
        }
      }
    }
#pragma unroll
    for (int n = 0; n < 4; ++n) {
      cs[n] += __shfl_xor(cs[n], 16, 64); cs[n] += __shfl_xor(cs[n], 32, 64);
      cq[n] += __shfl_xor(cq[n], 16, 64); cq[n] += __shfl_xor(cq[n], 32, 64);
    }
    if (lg == 0) {
#pragma unroll
      for (int n = 0; n < 4; ++n) {
        int gc = col0 + wc + n * 16 + lr;
        atomicAdd(&colsum[gc], cs[n]);
        atomicAdd(&colsq[gc], cq[n]);
      }
    }
  } else {
#pragma unroll
    for (int n = 0; n < 4; ++n) {
      int gc = col0 + wc + n * 16 + lr;
      float bv = bias[gc];
#pragma unroll
      for (int m = 0; m < 4; ++m) {
        int grb = row0 + wr + m * 16 + lg * 4;
#pragma unroll
        for (int j = 0; j < 4; ++j) {
          int gr = grb + j;
          if (gr < NN) {
            float v = acc[m][n][j] + bv;
            if constexpr (MODE == 1) v = fmaxf(v, 0.f);
            Hout[(size_t)gr * NC + gc] = v;
          }
        }
      }
    }
  }
}

// ---------------- BN finalize ----------------
__global__ void k_bnfin(const float* __restrict__ colsum, const float* __restrict__ colsq,
    const float* __restrict__ gamma, const float* __restrict__ beta,
    float* __restrict__ scale, float* __restrict__ shift) {
  int c = threadIdx.x;
  float inv_n = 1.0f / (float)NN;
  float mu = colsum[c] * inv_n;
  float var = colsq[c] * inv_n - mu * mu;
  float rstd = rsqrtf(var + 1e-5f);
  float sc = rstd * gamma[c];
  scale[c] = sc;
  shift[c] = beta[c] - mu * sc;
}

extern "C" void kernel_launch(void* const* d_in, const int* in_sizes, int n_in,
                              void* d_out, int out_size, void* d_ws, size_t ws_size,
                              hipStream_t stream) {
  (void)in_sizes; (void)n_in; (void)out_size; (void)ws_size;
  const int* node_ids    = (const int*)d_in[0];
  const int* node_depth  = (const int*)d_in[1];
  const int* edge_index  = (const int*)d_in[2];
  const float* edge_attr = (const float*)d_in[3];
  const float* temb      = (const float*)d_in[4];
  const float* demb      = (const float*)d_in[5];
  const float* We        = (const float*)d_in[6];
  const float* be        = (const float*)d_in[7];
  const float* W1        = (const float*)d_in[8];
  const float* b1        = (const float*)d_in[9];
  const float* gamma_    = (const float*)d_in[10];
  const float* beta_     = (const float*)d_in[11];
  const float* W2        = (const float*)d_in[12];
  const float* b2        = (const float*)d_in[13];
  const float* epsp      = (const float*)d_in[14];
  float* h = (float*)d_out;

  char* ws = (char*)d_ws;
  size_t off = 0;
  auto alloc = [&](size_t bytes) -> void* {
    void* p = ws + off;
    off = (off + bytes + 255) & ~(size_t)255;
    return p;
  };
  unsigned short* z   = (unsigned short*)alloc(2ull * NN * EMB);        // 25.6 MB
  unsigned short* y   = (unsigned short*)alloc(2ull * NN * HID);        // 51.2 MB
  unsigned short* W1t = (unsigned short*)alloc(2ull * NL * EMB * HID);  // 1.3 MB
  unsigned short* W2t = (unsigned short*)alloc(2ull * NL * HID * EMB);  // 1.3 MB
  int* deg      = (int*)alloc(sizeof(int) * NN);
  int* row_off  = (int*)alloc(sizeof(int) * (NN + 1));
  int* cursor   = (int*)alloc(sizeof(int) * NN);
  int* ssrc     = (int*)alloc(sizeof(int) * NE);
  float2* sattr = (float2*)alloc(sizeof(float2) * NE);
  int* bsums    = (int*)alloc(sizeof(int) * 256);
  float* colsum = (float*)alloc(sizeof(float) * HID * 2);
  float* colsq  = colsum + HID;
  float* scale  = (float*)alloc(sizeof(float) * HID);
  float* shift  = (float*)alloc(sizeof(float) * HID);

  const int* e_src = edge_index;
  const int* e_dst = edge_index + NE;

  k_init_h<<<(NN * 64) / 256, 256, 0, stream>>>(node_ids, node_depth, temb, demb, h);
  hipMemsetAsync(deg, 0, sizeof(int) * NN, stream);
  k_count<<<(NE + 255) / 256, 256, 0, stream>>>(e_dst, deg);
  k_scan1<<<49, 256, 0, stream>>>(deg, row_off, bsums);
  k_scan2<<<1, 256, 0, stream>>>(bsums, 49);
  k_scan3<<<49, 256, 0, stream>>>(row_off, bsums);
  k_copy<<<(NN + 255) / 256, 256, 0, stream>>>(row_off, cursor);
  k_fill<<<(NE + 255) / 256, 256, 0, stream>>>(e_src, e_dst, edge_attr, cursor, ssrc, sattr);
  // weights: W1 [L][EMB][HID] -> W1t [L][HID][EMB]; W2 [L][HID][EMB] -> W2t [L][EMB][HID]
  k_convW<<<dim3(HID / 32, EMB / 32, NL), 256, 0, stream>>>(W1, W1t, EMB, HID);
  k_convW<<<dim3(EMB / 32, HID / 32, NL), 256, 0, stream>>>(W2, W2t, HID, EMB);

  const int MB = (NN + 127) / 128;  // 391
  for (int l = 0; l < NL; ++l) {
    k_aggregate<<<(NN * 64) / 256, 256, 0, stream>>>(
        h, row_off, ssrc, sattr, We + (size_t)l * 2 * EMB, be + (size_t)l * EMB, epsp, l, z);
    hipMemsetAsync(colsum, 0, sizeof(float) * HID * 2, stream);
    k_mfma_gemm<EMB, HID, 0><<<dim3(MB, HID / 128), 256, 0, stream>>>(
        z, W1t + (size_t)l * EMB * HID, b1 + (size_t)l * HID,
        nullptr, nullptr, y, nullptr, colsum, colsq);
    k_bnfin<<<1, HID, 0, stream>>>(colsum, colsq, gamma_ + (size_t)l * HID,
                                   beta_ + (size_t)l * HID, scale, shift);
    if (l < NL - 1)
      k_mfma_gemm<HID, EMB, 1><<<dim3(MB, EMB / 128), 256, 0, stream>>>(
          y, W2t + (size_t)l * HID * EMB, b2 + (size_t)l * EMB,
          scale, shift, nullptr, h, nullptr, nullptr);
    else
      k_mfma_gemm<HID, EMB, 2><<<dim3(MB, EMB / 128), 256, 0, stream>>>(
          y, W2t + (size_t)l * HID * EMB, b2 + (size_t)l * EMB,
          scale, shift, nullptr, h, nullptr, nullptr);
  }
}